// Round 6
// baseline (123.948 us; speedup 1.0000x reference)
//
#include <hip/hip_runtime.h>

#define VQ_EPS    1e-12f
#define VQ_WINDOW 0.01f     // >= ~14 sigma of the bf16 score error; proven R6-R10 (absmax 0)
#define VQ_CAP    12

typedef short bf16x8 __attribute__((ext_vector_type(8)));   // 8 bf16 bit-patterns = 4 VGPRs
typedef float f32x4  __attribute__((ext_vector_type(4)));

static __device__ __forceinline__ unsigned short f2bf(float f) {
    unsigned u = __float_as_uint(f);
    u += 0x7fffu + ((u >> 16) & 1u);     // RNE
    return (unsigned short)(u >> 16);
}

// Order-preserving float->uint map (handles negative exact scores).
static __device__ __forceinline__ unsigned f2ord(float f) {
    unsigned b = __float_as_uint(f);
    return (b & 0x80000000u) ? ~b : (b | 0x80000000u);
}

// Wave-local LDS fence (proven R14, absmax 0): drains this wave's DS ops and
// stops compiler reordering. Sufficient for slot traffic produced AND
// consumed by the same wave (all of scnt/slist/spack -- indices derive from
// wid only).
static __device__ __forceinline__ void wave_lds_fence() {
    asm volatile("s_waitcnt lgkmcnt(0)" ::: "memory");
}

// Prep kernel: normalize codebook rows (fp32, mirrors F.normalize), emit:
//   cbn  [512][64] fp32      -- exact rescore + codes-gather epilogue
//   cbB  [32 ntile][2 kstep][64 lane][8] bf16 -- B-fragment-linear for
//        mfma_f32_16x16x32_bf16 (layout proven correct R5-R10)
//   kn2  [512] fp32          -- sum(cbn^2) AFTER normalization (reference rounding)
//   kn2p [512] fp32          -- kn2 + 2.0f (keeps approx scores > 0 for uint packing)
__global__ __launch_bounds__(64) void cb_prep_kernel(const float* __restrict__ cb,
                                                     float* __restrict__ cbn,
                                                     unsigned short* __restrict__ cbB,
                                                     float* __restrict__ kn2,
                                                     float* __restrict__ kn2p) {
    const int k = blockIdx.x;       // 512 codes
    const int c = threadIdx.x;      // 64 channels
    float v = cb[k * 64 + c];
    float s = v * v;
    #pragma unroll
    for (int off = 32; off > 0; off >>= 1) s += __shfl_xor(s, off, 64);
    float n = sqrtf(s);
    float cn = v / fmaxf(n, VQ_EPS);
    cbn[k * 64 + c] = cn;

    const int ntile = k >> 4, col = k & 15;
    const int ks = c >> 5, quad = (c >> 3) & 3, j = c & 7;
    cbB[(((ntile * 2 + ks) * 64) + quad * 16 + col) * 8 + j] = f2bf(cn);

    float s2 = cn * cn;
    #pragma unroll
    for (int off = 32; off > 0; off >>= 1) s2 += __shfl_xor(s2, off, 64);
    if (c == 0) { kn2[k] = s2; kn2p[k] = s2 + 2.0f; }
}

// Main kernel R16 (= R15 verbatim resubmit; R15's bench died with the same
// infra signature as R11, which R14 later proved was NOT kernel-caused).
// 512 blocks x 512 thr (8 waves), TWO rows per wave (A,B).
// Rationale: 2048 rows x 4 waves/row = 8192 waves = exactly one
// full-occupancy generation -- no backfill exists, and identical per-wave
// timelines phase-lock the whole chip (HBM burst -> VALU phase w/ HBM idle
// -> HBM burst). R14 proved barrier removal alone doesn't break this. Fix:
// software-pipeline the phases WITHIN each wave across two rows:
//   issue gatherA -> stage cbB -> B0 -> scanA (gatherB in flight under it)
//   -> collectA -> rescoreA -> epilogueA stores (fire-and-forget)
//   -> scanB (overlaps A's store drain) -> collectB -> rescoreB -> epilogueB
// All scoring/window/rescore machinery is R14 verbatim, duplicated with
// static A/B naming (no runtime-indexed state). 16 waves/CU (4/SIMD,
// VGPR<=128 via launch_bounds) -- TLP halves but per-wave ILP now covers
// the phase gaps TLP never did.
// Safety recipe (R8/R9/R14, proven): shfls/ballot only in uniform code;
// slot init + candidate pushes wave-owned; rescore per-lane only;
// wave-local fences for same-wave slot traffic; B0 covers staging.
__global__ __launch_bounds__(512, 4) void vq_mfma_kernel(const float* __restrict__ x,
                                                      const float* __restrict__ cbn,
                                                      const unsigned short* __restrict__ cbB,
                                                      const float* __restrict__ kn2,
                                                      const float* __restrict__ kn2p,
                                                      float* __restrict__ codes,
                                                      float* __restrict__ idxout) {
    __shared__ __align__(16) unsigned short lcb[32768];   // 64 KB staged cbB
    __shared__ unsigned long long spack[256];             // 2 KB
    __shared__ int slist[256][VQ_CAP];                    // 12 KB
    __shared__ int scnt[256];                             // 1 KB   -> 79 KB total

    const int t    = threadIdx.x;
    const int lane = t & 63;
    const int wid  = t >> 6;          // 0..7
    const int col  = lane & 15;
    const int quad = lane >> 4;
    const int wr   = wid & 3;         // wave within its row-quad
    const int rsel = wid >> 2;        // 0..1: which A-row of the block
    const int wpix = wr * 16 + col;   // col-group's pixel (w coordinate)

    const int pbaseA = rsel * 64;           // LDS pixel-slot bases
    const int pbaseB = pbaseA + 128;
    const int pslotA = pbaseA + wpix;
    const int pslotB = pbaseB + wpix;

    // Block covers 4 consecutive rows: waves 0-3 -> rows {0 (A), 2 (B)},
    // waves 4-7 -> rows {1 (A), 3 (B)}.
    const int rowidA = blockIdx.x * 4 + rsel;       // 0..2047 = (b,h)
    const int rowidB = rowidA + 2;
    const int bA = rowidA >> 6, hA = rowidA & 63;
    const int bB = rowidB >> 6, hB = rowidB & 63;
    const float* xblkA = x + ((size_t)bA << 18) + (hA << 6);   // + c*4096 + w
    const float* xblkB = x + ((size_t)bB << 18) + (hB << 6);

    if (quad == 0) {
        scnt[pslotA] = 0; spack[pslotA] = 0xFFFFFFFFFFFFFFFFull;
        scnt[pslotB] = 0; spack[pslotB] = 0xFFFFFFFFFFFFFFFFull;
    }

    // ---- issue row-A gather first (latency hides under staging + B0) ----
    float xvA[16];
    #pragma unroll
    for (int ks = 0; ks < 2; ++ks)
        #pragma unroll
        for (int j = 0; j < 8; ++j)
            xvA[ks * 8 + j] = xblkA[(size_t)(ks * 32 + quad * 8 + j) * 4096 + wpix];

    // ---- stage cbB -> LDS: 512 thr x 8 x 16 B, linear, coalesced ----
    {
        const uint4* g4 = (const uint4*)cbB;
        uint4*       l4 = (uint4*)lcb;
        #pragma unroll
        for (int r = 0; r < 8; ++r) l4[r * 512 + t] = g4[r * 512 + t];
    }

    __syncthreads();   // B0: staged cbB (and slot init) visible to all 8 waves

    // ---- row-A prolog: norm + A fragments ----
    float sspA = 0.0f;
    #pragma unroll
    for (int i = 0; i < 16; ++i) sspA = fmaf(xvA[i], xvA[i], sspA);
    sspA += __shfl_xor(sspA, 16);    // uniform code: all 64 lanes execute
    sspA += __shfl_xor(sspA, 32);
    const float m2aA = -2.0f * (1.0f / fmaxf(sqrtf(sspA), VQ_EPS));
    float m2rA[4];
    #pragma unroll
    for (int r = 0; r < 4; ++r) m2rA[r] = __shfl(m2aA, quad * 4 + r);  // uniform
    const float m2PA = __shfl(m2aA, lane >> 2);

    bf16x8 afragA[2];
    #pragma unroll
    for (int ks = 0; ks < 2; ++ks)
        #pragma unroll
        for (int j = 0; j < 8; ++j)
            ((unsigned short*)&afragA[ks])[j] = f2bf(xvA[ks * 8 + j]);

    // ---- issue row-B gather: flies under scanA ----
    float xvB[16];
    #pragma unroll
    for (int ks = 0; ks < 2; ++ks)
        #pragma unroll
        for (int j = 0; j < 8; ++j)
            xvB[ks * 8 + j] = xblkB[(size_t)(ks * 32 + quad * 8 + j) * 4096 + wpix];

    const bf16x8* lBf = (const bf16x8*)lcb;

    // ================= ROW A: scan / collect =================
    unsigned run1A[4] = {0xFFFFFFFFu, 0xFFFFFFFFu, 0xFFFFFFFFu, 0xFFFFFFFFu};
    unsigned run2A[4] = {0xFFFFFFFFu, 0xFFFFFFFFu, 0xFFFFFFFFu, 0xFFFFFFFFu};
    #pragma unroll 4
    for (int nt = 0; nt < 32; ++nt) {
        bf16x8 b0 = lBf[(nt * 2 + 0) * 64 + lane];     // ds_read_b128, conflict-free
        bf16x8 b1 = lBf[(nt * 2 + 1) * 64 + lane];
        f32x4 c = {0.0f, 0.0f, 0.0f, 0.0f};
        c = __builtin_amdgcn_mfma_f32_16x16x32_bf16(afragA[0], b0, c, 0, 0, 0);
        c = __builtin_amdgcn_mfma_f32_16x16x32_bf16(afragA[1], b1, c, 0, 0, 0);
        const float    kn   = kn2p[nt * 16 + col];     // L1-hot
        const unsigned kidx = (unsigned)(nt * 16 + col);
        #pragma unroll
        for (int r = 0; r < 4; ++r) {
            float s = fmaf(m2rA[r], c[r], kn);         // (~0.6, 5.2) -> uint-orderable
            unsigned key = (__float_as_uint(s) & 0xFFFFFE00u) | kidx;  // 9-bit k field
            unsigned mx  = max(run1A[r], key);
            run1A[r] = min(run1A[r], key);
            run2A[r] = min(run2A[r], mx);              // 2nd-smallest key
        }
    }

    float thrA[4];
    #pragma unroll
    for (int r = 0; r < 4; ++r) {
        unsigned v = run1A[r];
        v = min(v, (unsigned)__shfl_xor((int)v, 1));
        v = min(v, (unsigned)__shfl_xor((int)v, 2));
        v = min(v, (unsigned)__shfl_xor((int)v, 4));
        v = min(v, (unsigned)__shfl_xor((int)v, 8));
        thrA[r] = __uint_as_float(v & 0xFFFFFE00u) + VQ_WINDOW;
    }

    bool fA = false;
    #pragma unroll
    for (int r = 0; r < 4; ++r)
        fA |= (__uint_as_float(run2A[r] & 0xFFFFFE00u) <= thrA[r]);
    const unsigned long long waveflagA = __ballot(fA);   // uniform code

    if (waveflagA != 0ull) {
        // fallback pass 2: bit-identical recompute from LDS
        #pragma unroll 4
        for (int nt = 0; nt < 32; ++nt) {
            bf16x8 b0 = lBf[(nt * 2 + 0) * 64 + lane];
            bf16x8 b1 = lBf[(nt * 2 + 1) * 64 + lane];
            f32x4 c = {0.0f, 0.0f, 0.0f, 0.0f};
            c = __builtin_amdgcn_mfma_f32_16x16x32_bf16(afragA[0], b0, c, 0, 0, 0);
            c = __builtin_amdgcn_mfma_f32_16x16x32_bf16(afragA[1], b1, c, 0, 0, 0);
            const float kn   = kn2p[nt * 16 + col];
            const int   kidx = nt * 16 + col;
            #pragma unroll
            for (int r = 0; r < 4; ++r) {
                float s = fmaf(m2rA[r], c[r], kn);
                if (s <= thrA[r]) {
                    int pix = pbaseA + wr * 16 + quad * 4 + r;   // wave-owned pixel
                    int pos = atomicAdd(&scnt[pix], 1);
                    if (pos < VQ_CAP) slist[pix][pos] = kidx;
                }
            }
        }
    } else {
        // fast path: candidates are exactly the in-window slot-min1s
        #pragma unroll
        for (int r = 0; r < 4; ++r) {
            float s1 = __uint_as_float(run1A[r] & 0xFFFFFE00u);
            if (s1 <= thrA[r]) {
                int pix = pbaseA + wr * 16 + quad * 4 + r;
                int pos = atomicAdd(&scnt[pix], 1);
                if (pos < VQ_CAP) slist[pix][pos] = (int)(run1A[r] & 0x1FFu);
            }
        }
    }
    wave_lds_fence();   // A-slot traffic is same-wave only

    // ---- row-B prolog (xvB arrived during scanA) ----
    float sspB = 0.0f;
    #pragma unroll
    for (int i = 0; i < 16; ++i) sspB = fmaf(xvB[i], xvB[i], sspB);
    sspB += __shfl_xor(sspB, 16);
    sspB += __shfl_xor(sspB, 32);
    const float m2aB = -2.0f * (1.0f / fmaxf(sqrtf(sspB), VQ_EPS));
    float m2rB[4];
    #pragma unroll
    for (int r = 0; r < 4; ++r) m2rB[r] = __shfl(m2aB, quad * 4 + r);
    const float m2PB = __shfl(m2aB, lane >> 2);

    bf16x8 afragB[2];
    #pragma unroll
    for (int ks = 0; ks < 2; ++ks)
        #pragma unroll
        for (int j = 0; j < 8; ++j)
            ((unsigned short*)&afragB[ks])[j] = f2bf(xvB[ks * 8 + j]);

    // ---- exact fp32 rescore A: 4 lanes/pixel, per-lane only ----
    {
        const int pw  = wr * 16 + (lane >> 2);
        const int P   = pbaseA + pw;
        const int sub = lane & 3;
        const int cnt = scnt[P];
        if (cnt > 1) {
            const float* xp = xblkA + pw;
            if (cnt <= VQ_CAP) {
                for (int i = sub; i < cnt; i += 4) {
                    const int k = slist[P][i];
                    const float* cr = cbn + (size_t)k * 64;
                    float dot = 0.0f;
                    #pragma unroll 8
                    for (int c = 0; c < 64; ++c)
                        dot = fmaf(xp[(size_t)c * 4096], cr[c], dot);  // R1 order
                    float s = fmaf(m2PA, dot, kn2[k]);
                    unsigned long long key =
                        ((unsigned long long)f2ord(s) << 32) | (unsigned)k;
                    atomicMin(&spack[P], key);
                }
            } else {   // pathological overflow: exact scan of all codes
                for (int k = sub; k < 512; k += 4) {
                    const float* cr = cbn + (size_t)k * 64;
                    float dot = 0.0f;
                    #pragma unroll 8
                    for (int c = 0; c < 64; ++c)
                        dot = fmaf(xp[(size_t)c * 4096], cr[c], dot);
                    float s = fmaf(m2PA, dot, kn2[k]);
                    unsigned long long key =
                        ((unsigned long long)f2ord(s) << 32) | (unsigned)k;
                    atomicMin(&spack[P], key);
                }
            }
        }
    }
    wave_lds_fence();   // A rescore results are same-wave too

    // ---- winner + epilogue A (stores fire-and-forget; scanB runs under drain) ----
    {
        const int cntw = scnt[pslotA];
        const int bk = (cntw == 1) ? slist[pslotA][0]
                                   : (int)(spack[pslotA] & 0xFFFFFFFFull);
        if (quad == 0) idxout[rowidA * 64 + wpix] = (float)bk;
        const float4* crow = (const float4*)(cbn + (size_t)bk * 64) + quad * 4;
        float* cp = codes + ((size_t)bA << 18) + (hA << 6) + wpix;
        #pragma unroll
        for (int q = 0; q < 4; ++q) {
            float4 v = crow[q];
            const int c0 = quad * 16 + q * 4;
            cp[(size_t)(c0 + 0) * 4096] = v.x;
            cp[(size_t)(c0 + 1) * 4096] = v.y;
            cp[(size_t)(c0 + 2) * 4096] = v.z;
            cp[(size_t)(c0 + 3) * 4096] = v.w;
        }
    }

    // ================= ROW B: scan / collect =================
    unsigned run1B[4] = {0xFFFFFFFFu, 0xFFFFFFFFu, 0xFFFFFFFFu, 0xFFFFFFFFu};
    unsigned run2B[4] = {0xFFFFFFFFu, 0xFFFFFFFFu, 0xFFFFFFFFu, 0xFFFFFFFFu};
    #pragma unroll 4
    for (int nt = 0; nt < 32; ++nt) {
        bf16x8 b0 = lBf[(nt * 2 + 0) * 64 + lane];
        bf16x8 b1 = lBf[(nt * 2 + 1) * 64 + lane];
        f32x4 c = {0.0f, 0.0f, 0.0f, 0.0f};
        c = __builtin_amdgcn_mfma_f32_16x16x32_bf16(afragB[0], b0, c, 0, 0, 0);
        c = __builtin_amdgcn_mfma_f32_16x16x32_bf16(afragB[1], b1, c, 0, 0, 0);
        const float    kn   = kn2p[nt * 16 + col];
        const unsigned kidx = (unsigned)(nt * 16 + col);
        #pragma unroll
        for (int r = 0; r < 4; ++r) {
            float s = fmaf(m2rB[r], c[r], kn);
            unsigned key = (__float_as_uint(s) & 0xFFFFFE00u) | kidx;
            unsigned mx  = max(run1B[r], key);
            run1B[r] = min(run1B[r], key);
            run2B[r] = min(run2B[r], mx);
        }
    }

    float thrB[4];
    #pragma unroll
    for (int r = 0; r < 4; ++r) {
        unsigned v = run1B[r];
        v = min(v, (unsigned)__shfl_xor((int)v, 1));
        v = min(v, (unsigned)__shfl_xor((int)v, 2));
        v = min(v, (unsigned)__shfl_xor((int)v, 4));
        v = min(v, (unsigned)__shfl_xor((int)v, 8));
        thrB[r] = __uint_as_float(v & 0xFFFFFE00u) + VQ_WINDOW;
    }

    bool fB = false;
    #pragma unroll
    for (int r = 0; r < 4; ++r)
        fB |= (__uint_as_float(run2B[r] & 0xFFFFFE00u) <= thrB[r]);
    const unsigned long long waveflagB = __ballot(fB);   // uniform code

    if (waveflagB != 0ull) {
        #pragma unroll 4
        for (int nt = 0; nt < 32; ++nt) {
            bf16x8 b0 = lBf[(nt * 2 + 0) * 64 + lane];
            bf16x8 b1 = lBf[(nt * 2 + 1) * 64 + lane];
            f32x4 c = {0.0f, 0.0f, 0.0f, 0.0f};
            c = __builtin_amdgcn_mfma_f32_16x16x32_bf16(afragB[0], b0, c, 0, 0, 0);
            c = __builtin_amdgcn_mfma_f32_16x16x32_bf16(afragB[1], b1, c, 0, 0, 0);
            const float kn   = kn2p[nt * 16 + col];
            const int   kidx = nt * 16 + col;
            #pragma unroll
            for (int r = 0; r < 4; ++r) {
                float s = fmaf(m2rB[r], c[r], kn);
                if (s <= thrB[r]) {
                    int pix = pbaseB + wr * 16 + quad * 4 + r;
                    int pos = atomicAdd(&scnt[pix], 1);
                    if (pos < VQ_CAP) slist[pix][pos] = kidx;
                }
            }
        }
    } else {
        #pragma unroll
        for (int r = 0; r < 4; ++r) {
            float s1 = __uint_as_float(run1B[r] & 0xFFFFFE00u);
            if (s1 <= thrB[r]) {
                int pix = pbaseB + wr * 16 + quad * 4 + r;
                int pos = atomicAdd(&scnt[pix], 1);
                if (pos < VQ_CAP) slist[pix][pos] = (int)(run1B[r] & 0x1FFu);
            }
        }
    }
    wave_lds_fence();   // B-slot traffic is same-wave only

    // ---- exact fp32 rescore B ----
    {
        const int pw  = wr * 16 + (lane >> 2);
        const int P   = pbaseB + pw;
        const int sub = lane & 3;
        const int cnt = scnt[P];
        if (cnt > 1) {
            const float* xp = xblkB + pw;
            if (cnt <= VQ_CAP) {
                for (int i = sub; i < cnt; i += 4) {
                    const int k = slist[P][i];
                    const float* cr = cbn + (size_t)k * 64;
                    float dot = 0.0f;
                    #pragma unroll 8
                    for (int c = 0; c < 64; ++c)
                        dot = fmaf(xp[(size_t)c * 4096], cr[c], dot);
                    float s = fmaf(m2PB, dot, kn2[k]);
                    unsigned long long key =
                        ((unsigned long long)f2ord(s) << 32) | (unsigned)k;
                    atomicMin(&spack[P], key);
                }
            } else {
                for (int k = sub; k < 512; k += 4) {
                    const float* cr = cbn + (size_t)k * 64;
                    float dot = 0.0f;
                    #pragma unroll 8
                    for (int c = 0; c < 64; ++c)
                        dot = fmaf(xp[(size_t)c * 4096], cr[c], dot);
                    float s = fmaf(m2PB, dot, kn2[k]);
                    unsigned long long key =
                        ((unsigned long long)f2ord(s) << 32) | (unsigned)k;
                    atomicMin(&spack[P], key);
                }
            }
        }
    }
    wave_lds_fence();   // B rescore results visible (same wave)

    // ---- winner + epilogue B ----
    {
        const int cntw = scnt[pslotB];
        const int bk = (cntw == 1) ? slist[pslotB][0]
                                   : (int)(spack[pslotB] & 0xFFFFFFFFull);
        if (quad == 0) idxout[rowidB * 64 + wpix] = (float)bk;
        const float4* crow = (const float4*)(cbn + (size_t)bk * 64) + quad * 4;
        float* cp = codes + ((size_t)bB << 18) + (hB << 6) + wpix;
        #pragma unroll
        for (int q = 0; q < 4; ++q) {
            float4 v = crow[q];
            const int c0 = quad * 16 + q * 4;
            cp[(size_t)(c0 + 0) * 4096] = v.x;
            cp[(size_t)(c0 + 1) * 4096] = v.y;
            cp[(size_t)(c0 + 2) * 4096] = v.z;
            cp[(size_t)(c0 + 3) * 4096] = v.w;
        }
    }
}

extern "C" void kernel_launch(void* const* d_in, const int* in_sizes, int n_in,
                              void* d_out, int out_size, void* d_ws, size_t ws_size,
                              hipStream_t stream) {
    const float* x  = (const float*)d_in[0];   // [32,64,64,64] fp32
    const float* cb = (const float*)d_in[1];   // [512,64] fp32

    float*          cbn  = (float*)d_ws;                       // 128 KB
    unsigned short* cbB  = (unsigned short*)(cbn + 512 * 64);  // 64 KB (frag-linear bf16)
    float*          kn2  = (float*)(cbB + 32768);              // 2 KB
    float*          kn2p = kn2 + 512;                          // 2 KB

    float* codes  = (float*)d_out;                             // 32*64*64*64 floats
    float* idxout = codes + (size_t)32 * 64 * 64 * 64;         // 131072 floats

    cb_prep_kernel<<<512, 64, 0, stream>>>(cb, cbn, cbB, kn2, kn2p);
    vq_mfma_kernel<<<512, 512, 0, stream>>>(x, cbn, cbB, kn2, kn2p, codes, idxout);
}

// Round 7
// 122.793 us; speedup vs baseline: 1.0094x; 1.0094x over previous
//
#include <hip/hip_runtime.h>

#define VQ_EPS    1e-12f
#define VQ_WINDOW 0.01f     // >= ~14 sigma of the bf16 score error; proven R6-R10 (absmax 0)
#define VQ_CAP    12

typedef short bf16x8 __attribute__((ext_vector_type(8)));   // 8 bf16 bit-patterns = 4 VGPRs
typedef float f32x4  __attribute__((ext_vector_type(4)));

static __device__ __forceinline__ unsigned short f2bf(float f) {
    unsigned u = __float_as_uint(f);
    u += 0x7fffu + ((u >> 16) & 1u);     // RNE
    return (unsigned short)(u >> 16);
}

// Order-preserving float->uint map (handles negative exact scores).
static __device__ __forceinline__ unsigned f2ord(float f) {
    unsigned b = __float_as_uint(f);
    return (b & 0x80000000u) ? ~b : (b | 0x80000000u);
}

// Wave-local LDS fence (proven R14, absmax 0): drains this wave's DS ops and
// stops compiler reordering. Sufficient for slot traffic produced AND
// consumed by the same wave (all of scnt/slist/spack -- indices derive from
// wid only).
static __device__ __forceinline__ void wave_lds_fence() {
    asm volatile("s_waitcnt lgkmcnt(0)" ::: "memory");
}

// Prep kernel: normalize codebook rows (fp32, mirrors F.normalize), emit:
//   cbn  [512][64] fp32      -- exact rescore + codes-gather epilogue
//   cbB  [32 ntile][2 kstep][64 lane][8] bf16 -- B-fragment-linear for
//        mfma_f32_16x16x32_bf16 (layout proven correct R5-R10)
//   kn2  [512] fp32          -- sum(cbn^2) AFTER normalization (reference rounding)
//   kn2p [512] fp32          -- kn2 + 2.0f (keeps approx scores > 0 for uint packing)
__global__ __launch_bounds__(64) void cb_prep_kernel(const float* __restrict__ cb,
                                                     float* __restrict__ cbn,
                                                     unsigned short* __restrict__ cbB,
                                                     float* __restrict__ kn2,
                                                     float* __restrict__ kn2p) {
    const int k = blockIdx.x;       // 512 codes
    const int c = threadIdx.x;      // 64 channels
    float v = cb[k * 64 + c];
    float s = v * v;
    #pragma unroll
    for (int off = 32; off > 0; off >>= 1) s += __shfl_xor(s, off, 64);
    float n = sqrtf(s);
    float cn = v / fmaxf(n, VQ_EPS);
    cbn[k * 64 + c] = cn;

    const int ntile = k >> 4, col = k & 15;
    const int ks = c >> 5, quad = (c >> 3) & 3, j = c & 7;
    cbB[(((ntile * 2 + ks) * 64) + quad * 16 + col) * 8 + j] = f2bf(cn);

    float s2 = cn * cn;
    #pragma unroll
    for (int off = 32; off > 0; off >>= 1) s2 += __shfl_xor(s2, off, 64);
    if (c == 0) { kn2[k] = s2; kn2p[k] = s2 + 2.0f; }
}

// Main kernel R17: 512 blocks x 512 thr (8 waves = 2 groups of 4), each wave
// scans its 16-px slice of TWO rows in ONE fused loop sharing the B-reads.
// Rationale: a wave64 ds_read_b128 costs ~12 cyc of CU LDS port time; R13's
// scan needed 256 KB of LDS reads per row (4 waves x 64 KB) ~= 13 us/CU --
// one of three stacked floors (VALU ~16 us, HBM phases ~24 us). Fusing two
// rows over the same b0/b1 halves the scan's LDS traffic (R16 pipelined two
// rows but in SEPARATE loops -- no LDS reuse -- and regressed; this is the
// corrected form). All scoring/window/rescore machinery is R14 verbatim,
// duplicated per row with shared kn/ds-reads (scores bit-identical).
// Safety recipe (R8/R9/R14, proven): shfls/ballot only in uniform code;
// slot init + candidate pushes wave-owned; rescore per-lane only;
// wave-local fences for same-wave slot traffic; B0 covers staging.
__global__ __launch_bounds__(512, 4) void vq_mfma_kernel(const float* __restrict__ x,
                                                      const float* __restrict__ cbn,
                                                      const unsigned short* __restrict__ cbB,
                                                      const float* __restrict__ kn2,
                                                      const float* __restrict__ kn2p,
                                                      float* __restrict__ codes,
                                                      float* __restrict__ idxout) {
    __shared__ __align__(16) unsigned short lcb[32768];   // 64 KB staged cbB
    __shared__ unsigned long long spack[256];             // 2 KB
    __shared__ int slist[256][VQ_CAP];                    // 12 KB
    __shared__ int scnt[256];                             // 1 KB   -> 79 KB total

    const int t    = threadIdx.x;
    const int lane = t & 63;
    const int wid  = t >> 6;          // 0..7
    const int col  = lane & 15;
    const int quad = lane >> 4;
    const int wr   = wid & 3;         // wave within its group
    const int grp  = wid >> 2;        // 0..1: row-pair of the block
    const int wpix = wr * 16 + col;   // col-group's pixel (w coordinate)

    const int rw0 = grp * 2;          // rows-within-block
    const int rw1 = rw0 + 1;
    const int pbase0 = rw0 * 64;      // LDS pixel-slot bases
    const int pbase1 = rw1 * 64;
    const int pslot0 = pbase0 + wpix;
    const int pslot1 = pbase1 + wpix;

    const int rowid0 = blockIdx.x * 4 + rw0;   // 0..2047 = (b,h)
    const int rowid1 = rowid0 + 1;
    const int b0r = rowid0 >> 6, h0 = rowid0 & 63;
    const int b1r = rowid1 >> 6, h1 = rowid1 & 63;
    const float* xblk0 = x + ((size_t)b0r << 18) + (h0 << 6);   // + c*4096 + w
    const float* xblk1 = x + ((size_t)b1r << 18) + (h1 << 6);

    if (quad == 0) {
        scnt[pslot0] = 0; spack[pslot0] = 0xFFFFFFFFFFFFFFFFull;
        scnt[pslot1] = 0; spack[pslot1] = 0xFFFFFFFFFFFFFFFFull;
    }

    // ---- gathers for BOTH rows issued up front (32 loads in flight;
    //      latency hides under the cbB staging + barrier) ----
    float xv0[16], xv1[16];
    #pragma unroll
    for (int ks = 0; ks < 2; ++ks)
        #pragma unroll
        for (int j = 0; j < 8; ++j)
            xv0[ks * 8 + j] = xblk0[(size_t)(ks * 32 + quad * 8 + j) * 4096 + wpix];
    #pragma unroll
    for (int ks = 0; ks < 2; ++ks)
        #pragma unroll
        for (int j = 0; j < 8; ++j)
            xv1[ks * 8 + j] = xblk1[(size_t)(ks * 32 + quad * 8 + j) * 4096 + wpix];

    // ---- stage cbB -> LDS: 512 thr x 8 x 16 B, linear, coalesced ----
    {
        const uint4* g4 = (const uint4*)cbB;
        uint4*       l4 = (uint4*)lcb;
        #pragma unroll
        for (int r = 0; r < 8; ++r) l4[r * 512 + t] = g4[r * 512 + t];
    }

    __syncthreads();   // B0: staged cbB (and slot init) visible to all 8 waves

    // ---- prologs: norms + A fragments for both rows ----
    float ssp0 = 0.0f, ssp1 = 0.0f;
    #pragma unroll
    for (int i = 0; i < 16; ++i) ssp0 = fmaf(xv0[i], xv0[i], ssp0);
    #pragma unroll
    for (int i = 0; i < 16; ++i) ssp1 = fmaf(xv1[i], xv1[i], ssp1);
    ssp0 += __shfl_xor(ssp0, 16);    // uniform code: all 64 lanes execute
    ssp0 += __shfl_xor(ssp0, 32);
    ssp1 += __shfl_xor(ssp1, 16);
    ssp1 += __shfl_xor(ssp1, 32);
    const float m2a0 = -2.0f * (1.0f / fmaxf(sqrtf(ssp0), VQ_EPS));
    const float m2a1 = -2.0f * (1.0f / fmaxf(sqrtf(ssp1), VQ_EPS));
    float m2r0[4], m2r1[4];
    #pragma unroll
    for (int r = 0; r < 4; ++r) m2r0[r] = __shfl(m2a0, quad * 4 + r);  // uniform
    #pragma unroll
    for (int r = 0; r < 4; ++r) m2r1[r] = __shfl(m2a1, quad * 4 + r);
    const float m2P0 = __shfl(m2a0, lane >> 2);   // uniform: rescore-pixel m2
    const float m2P1 = __shfl(m2a1, lane >> 2);

    bf16x8 afrag0[2], afrag1[2];
    #pragma unroll
    for (int ks = 0; ks < 2; ++ks)
        #pragma unroll
        for (int j = 0; j < 8; ++j) {
            ((unsigned short*)&afrag0[ks])[j] = f2bf(xv0[ks * 8 + j]);
            ((unsigned short*)&afrag1[ks])[j] = f2bf(xv1[ks * 8 + j]);
        }

    const bf16x8* lBf = (const bf16x8*)lcb;

    // ---- fused pass 1: one B-read pair feeds BOTH rows' MFMAs ----
    unsigned run1_0[4] = {0xFFFFFFFFu, 0xFFFFFFFFu, 0xFFFFFFFFu, 0xFFFFFFFFu};
    unsigned run2_0[4] = {0xFFFFFFFFu, 0xFFFFFFFFu, 0xFFFFFFFFu, 0xFFFFFFFFu};
    unsigned run1_1[4] = {0xFFFFFFFFu, 0xFFFFFFFFu, 0xFFFFFFFFu, 0xFFFFFFFFu};
    unsigned run2_1[4] = {0xFFFFFFFFu, 0xFFFFFFFFu, 0xFFFFFFFFu, 0xFFFFFFFFu};
    #pragma unroll 2
    for (int nt = 0; nt < 32; ++nt) {
        bf16x8 b0 = lBf[(nt * 2 + 0) * 64 + lane];     // ds_read_b128, conflict-free
        bf16x8 b1 = lBf[(nt * 2 + 1) * 64 + lane];
        f32x4 c0 = {0.0f, 0.0f, 0.0f, 0.0f};
        f32x4 c1 = {0.0f, 0.0f, 0.0f, 0.0f};
        c0 = __builtin_amdgcn_mfma_f32_16x16x32_bf16(afrag0[0], b0, c0, 0, 0, 0);
        c1 = __builtin_amdgcn_mfma_f32_16x16x32_bf16(afrag1[0], b0, c1, 0, 0, 0);
        c0 = __builtin_amdgcn_mfma_f32_16x16x32_bf16(afrag0[1], b1, c0, 0, 0, 0);
        c1 = __builtin_amdgcn_mfma_f32_16x16x32_bf16(afrag1[1], b1, c1, 0, 0, 0);
        const float    kn   = kn2p[nt * 16 + col];     // L1-hot, shared by rows
        const unsigned kidx = (unsigned)(nt * 16 + col);
        #pragma unroll
        for (int r = 0; r < 4; ++r) {
            float s0 = fmaf(m2r0[r], c0[r], kn);       // (~0.6, 5.2) -> uint-orderable
            unsigned key0 = (__float_as_uint(s0) & 0xFFFFFE00u) | kidx;  // 9-bit k
            unsigned mx0  = max(run1_0[r], key0);
            run1_0[r] = min(run1_0[r], key0);
            run2_0[r] = min(run2_0[r], mx0);           // 2nd-smallest key
            float s1 = fmaf(m2r1[r], c1[r], kn);
            unsigned key1 = (__float_as_uint(s1) & 0xFFFFFE00u) | kidx;
            unsigned mx1  = max(run1_1[r], key1);
            run1_1[r] = min(run1_1[r], key1);
            run2_1[r] = min(run2_1[r], mx1);
        }
    }

    // ---- thresholds per row: cross-lane min within 16-lane col group ----
    float thr0[4], thr1[4];
    #pragma unroll
    for (int r = 0; r < 4; ++r) {
        unsigned v = run1_0[r];
        v = min(v, (unsigned)__shfl_xor((int)v, 1));
        v = min(v, (unsigned)__shfl_xor((int)v, 2));
        v = min(v, (unsigned)__shfl_xor((int)v, 4));
        v = min(v, (unsigned)__shfl_xor((int)v, 8));
        thr0[r] = __uint_as_float(v & 0xFFFFFE00u) + VQ_WINDOW;
        unsigned w = run1_1[r];
        w = min(w, (unsigned)__shfl_xor((int)w, 1));
        w = min(w, (unsigned)__shfl_xor((int)w, 2));
        w = min(w, (unsigned)__shfl_xor((int)w, 4));
        w = min(w, (unsigned)__shfl_xor((int)w, 8));
        thr1[r] = __uint_as_float(w & 0xFFFFFE00u) + VQ_WINDOW;
    }

    // ---- wave flag over BOTH rows' slots (conservative; uniform) ----
    bool f = false;
    #pragma unroll
    for (int r = 0; r < 4; ++r) {
        f |= (__uint_as_float(run2_0[r] & 0xFFFFFE00u) <= thr0[r]);
        f |= (__uint_as_float(run2_1[r] & 0xFFFFFE00u) <= thr1[r]);
    }
    const unsigned long long waveflag = __ballot(f);   // uniform code

    if (waveflag != 0ull) {
        // ---- fused fallback pass 2: bit-identical recompute, both rows ----
        #pragma unroll 2
        for (int nt = 0; nt < 32; ++nt) {
            bf16x8 b0 = lBf[(nt * 2 + 0) * 64 + lane];
            bf16x8 b1 = lBf[(nt * 2 + 1) * 64 + lane];
            f32x4 c0 = {0.0f, 0.0f, 0.0f, 0.0f};
            f32x4 c1 = {0.0f, 0.0f, 0.0f, 0.0f};
            c0 = __builtin_amdgcn_mfma_f32_16x16x32_bf16(afrag0[0], b0, c0, 0, 0, 0);
            c1 = __builtin_amdgcn_mfma_f32_16x16x32_bf16(afrag1[0], b0, c1, 0, 0, 0);
            c0 = __builtin_amdgcn_mfma_f32_16x16x32_bf16(afrag0[1], b1, c0, 0, 0, 0);
            c1 = __builtin_amdgcn_mfma_f32_16x16x32_bf16(afrag1[1], b1, c1, 0, 0, 0);
            const float kn   = kn2p[nt * 16 + col];
            const int   kidx = nt * 16 + col;
            #pragma unroll
            for (int r = 0; r < 4; ++r) {
                float s0 = fmaf(m2r0[r], c0[r], kn);
                if (s0 <= thr0[r]) {
                    int pix = pbase0 + wr * 16 + quad * 4 + r;   // wave-owned pixel
                    int pos = atomicAdd(&scnt[pix], 1);
                    if (pos < VQ_CAP) slist[pix][pos] = kidx;
                }
                float s1 = fmaf(m2r1[r], c1[r], kn);
                if (s1 <= thr1[r]) {
                    int pix = pbase1 + wr * 16 + quad * 4 + r;
                    int pos = atomicAdd(&scnt[pix], 1);
                    if (pos < VQ_CAP) slist[pix][pos] = kidx;
                }
            }
        }
    } else {
        // ---- fast path: candidates are exactly the in-window slot-min1s ----
        #pragma unroll
        for (int r = 0; r < 4; ++r) {
            float s0 = __uint_as_float(run1_0[r] & 0xFFFFFE00u);
            if (s0 <= thr0[r]) {
                int pix = pbase0 + wr * 16 + quad * 4 + r;
                int pos = atomicAdd(&scnt[pix], 1);
                if (pos < VQ_CAP) slist[pix][pos] = (int)(run1_0[r] & 0x1FFu);
            }
            float s1 = __uint_as_float(run1_1[r] & 0xFFFFFE00u);
            if (s1 <= thr1[r]) {
                int pix = pbase1 + wr * 16 + quad * 4 + r;
                int pos = atomicAdd(&scnt[pix], 1);
                if (pos < VQ_CAP) slist[pix][pos] = (int)(run1_1[r] & 0x1FFu);
            }
        }
    }
    wave_lds_fence();   // slot traffic above is same-wave only

    // ---- exact fp32 rescore, row 0 then row 1 (4 lanes/pixel, per-lane) ----
    {
        const int pw  = wr * 16 + (lane >> 2);    // this lane's rescore pixel (w)
        const int sub = lane & 3;
        {
            const int P   = pbase0 + pw;
            const int cnt = scnt[P];
            if (cnt > 1) {
                const float* xp = xblk0 + pw;
                if (cnt <= VQ_CAP) {
                    for (int i = sub; i < cnt; i += 4) {
                        const int k = slist[P][i];
                        const float* cr = cbn + (size_t)k * 64;
                        float dot = 0.0f;
                        #pragma unroll 8
                        for (int c = 0; c < 64; ++c)
                            dot = fmaf(xp[(size_t)c * 4096], cr[c], dot);  // R1 order
                        float s = fmaf(m2P0, dot, kn2[k]);
                        unsigned long long key =
                            ((unsigned long long)f2ord(s) << 32) | (unsigned)k;
                        atomicMin(&spack[P], key);
                    }
                } else {   // pathological overflow: exact scan of all codes
                    for (int k = sub; k < 512; k += 4) {
                        const float* cr = cbn + (size_t)k * 64;
                        float dot = 0.0f;
                        #pragma unroll 8
                        for (int c = 0; c < 64; ++c)
                            dot = fmaf(xp[(size_t)c * 4096], cr[c], dot);
                        float s = fmaf(m2P0, dot, kn2[k]);
                        unsigned long long key =
                            ((unsigned long long)f2ord(s) << 32) | (unsigned)k;
                        atomicMin(&spack[P], key);
                    }
                }
            }
        }
        {
            const int P   = pbase1 + pw;
            const int cnt = scnt[P];
            if (cnt > 1) {
                const float* xp = xblk1 + pw;
                if (cnt <= VQ_CAP) {
                    for (int i = sub; i < cnt; i += 4) {
                        const int k = slist[P][i];
                        const float* cr = cbn + (size_t)k * 64;
                        float dot = 0.0f;
                        #pragma unroll 8
                        for (int c = 0; c < 64; ++c)
                            dot = fmaf(xp[(size_t)c * 4096], cr[c], dot);
                        float s = fmaf(m2P1, dot, kn2[k]);
                        unsigned long long key =
                            ((unsigned long long)f2ord(s) << 32) | (unsigned)k;
                        atomicMin(&spack[P], key);
                    }
                } else {
                    for (int k = sub; k < 512; k += 4) {
                        const float* cr = cbn + (size_t)k * 64;
                        float dot = 0.0f;
                        #pragma unroll 8
                        for (int c = 0; c < 64; ++c)
                            dot = fmaf(xp[(size_t)c * 4096], cr[c], dot);
                        float s = fmaf(m2P1, dot, kn2[k]);
                        unsigned long long key =
                            ((unsigned long long)f2ord(s) << 32) | (unsigned)k;
                        atomicMin(&spack[P], key);
                    }
                }
            }
        }
    }
    wave_lds_fence();   // rescore results are same-wave too

    // ---- winners + epilogues (row 0, then row 1) ----
    {
        const int cntw = scnt[pslot0];
        const int bk = (cntw == 1) ? slist[pslot0][0]
                                   : (int)(spack[pslot0] & 0xFFFFFFFFull);
        if (quad == 0) idxout[rowid0 * 64 + wpix] = (float)bk;
        const float4* crow = (const float4*)(cbn + (size_t)bk * 64) + quad * 4;
        float* cp = codes + ((size_t)b0r << 18) + (h0 << 6) + wpix;
        #pragma unroll
        for (int q = 0; q < 4; ++q) {
            float4 v = crow[q];
            const int c0 = quad * 16 + q * 4;
            cp[(size_t)(c0 + 0) * 4096] = v.x;
            cp[(size_t)(c0 + 1) * 4096] = v.y;
            cp[(size_t)(c0 + 2) * 4096] = v.z;
            cp[(size_t)(c0 + 3) * 4096] = v.w;
        }
    }
    {
        const int cntw = scnt[pslot1];
        const int bk = (cntw == 1) ? slist[pslot1][0]
                                   : (int)(spack[pslot1] & 0xFFFFFFFFull);
        if (quad == 0) idxout[rowid1 * 64 + wpix] = (float)bk;
        const float4* crow = (const float4*)(cbn + (size_t)bk * 64) + quad * 4;
        float* cp = codes + ((size_t)b1r << 18) + (h1 << 6) + wpix;
        #pragma unroll
        for (int q = 0; q < 4; ++q) {
            float4 v = crow[q];
            const int c0 = quad * 16 + q * 4;
            cp[(size_t)(c0 + 0) * 4096] = v.x;
            cp[(size_t)(c0 + 1) * 4096] = v.y;
            cp[(size_t)(c0 + 2) * 4096] = v.z;
            cp[(size_t)(c0 + 3) * 4096] = v.w;
        }
    }
}

extern "C" void kernel_launch(void* const* d_in, const int* in_sizes, int n_in,
                              void* d_out, int out_size, void* d_ws, size_t ws_size,
                              hipStream_t stream) {
    const float* x  = (const float*)d_in[0];   // [32,64,64,64] fp32
    const float* cb = (const float*)d_in[1];   // [512,64] fp32

    float*          cbn  = (float*)d_ws;                       // 128 KB
    unsigned short* cbB  = (unsigned short*)(cbn + 512 * 64);  // 64 KB (frag-linear bf16)
    float*          kn2  = (float*)(cbB + 32768);              // 2 KB
    float*          kn2p = kn2 + 512;                          // 2 KB

    float* codes  = (float*)d_out;                             // 32*64*64*64 floats
    float* idxout = codes + (size_t)32 * 64 * 64 * 64;         // 131072 floats

    cb_prep_kernel<<<512, 64, 0, stream>>>(cb, cbn, cbB, kn2, kn2p);
    vq_mfma_kernel<<<512, 512, 0, stream>>>(x, cbn, cbB, kn2, kn2p, codes, idxout);
}